// Round 5
// baseline (75.376 us; speedup 1.0000x reference)
//
#include <hip/hip_runtime.h>
#include <cmath>

// Problem constants (match reference)
#define BB 4
#define NN 48
#define PP (NN * NN)   // 2304 (x,y) pairs per plane
#define TT 33
#define RR 16
#define NC 80
#define NI 5
#define NEG (-1000.0f)

// chain_dp decomposition: x-split 2
#define XS 24          // x-range per block
#define XP 25          // padded stride for [k][x_local] tiles (gcd(25,32)=1)

// ---------------------------------------------------------------------------
// Kernel 0: transpose trans [B, 2304, 33] -> tpose [B, 33, 2304] so every
// hop-plane becomes a contiguous 9 KB block (enables cheap coalesced staging,
// which is what makes the x-split below nearly free).
// ---------------------------------------------------------------------------
__global__ __launch_bounds__(256) void transpose_kernel(
    const float* __restrict__ trans,   // [B, 2304, 33]
    float*       __restrict__ tpose)   // [B, 33, 2304]
{
    __shared__ float tile[64 * TT];    // 64 p x 33 t
    const int blk = blockIdx.x;        // B * 36
    const int b   = blk / 36;
    const int p0  = (blk - b * 36) * 64;

    const float4* src = (const float4*)(trans + ((size_t)b * PP + p0) * TT);
    for (int j = threadIdx.x; j < 64 * TT / 4; j += 256)
        ((float4*)tile)[j] = src[j];
    __syncthreads();

    for (int j = threadIdx.x; j < TT * 64; j += 256) {
        const int t  = j >> 6;
        const int pl = j & 63;
        tpose[((size_t)b * TT + t) * PP + p0 + pl] = tile[pl * TT + t];
    }
}

// ---------------------------------------------------------------------------
// Kernel 1: per-(b,c,x-half) tropical chain DP.
//   Block covers x-range 24, all 48 y.  192 threads = 8 x-tiles (3 wide) x
//   24 y-tiles (2 wide); 3x2 register tile each.  Both max-plus products are
//   x-local, so the split has no cross-block coupling; only H1/H2 staging is
//   duplicated (coalesced from tpose -> cheap).
//   k-steps paired so fmax(acc, fmax(t0,t1)) folds to v_max3_f32.
// ---------------------------------------------------------------------------
__global__ __launch_bounds__(192) void chain_dp_kernel(
    const float* __restrict__ tpose,    // [B, 33, 2304]
    const int*   __restrict__ rules,    // [Nc,3]
    const float* __restrict__ weights,  // [Nc]
    float*       __restrict__ sw)       // [B,Nc,N,N]
{
    __shared__ float H0T[NN * XP];  // A of product 1, [k][x_local]
    __shared__ float H1 [PP];       // B of product 1, [k][y]
    __shared__ float H2 [PP];       // B of product 2, [k][y]
    __shared__ float S1T[NN * XP];  // A of product 2, [k][x_local]

    const int blk = blockIdx.x;     // 640 = 320 (b,c) x 2 x-halves
    const int bc  = blk >> 1;
    const int xh  = blk & 1;
    const int b   = bc / NC;
    const int c   = bc - b * NC;
    const int xbase = xh * XS;

    const int r0 = rules[c * 3 + 0];
    const int r1 = rules[c * 3 + 1];
    const int r2 = rules[c * 3 + 2];

    const float* p0 = tpose + ((size_t)b * TT + r0) * PP + xbase * NN;
    const float* p1 = tpose + ((size_t)b * TT + r1) * PP;
    const float* p2 = tpose + ((size_t)b * TT + r2) * PP;

    // Coalesced staging. H1/H2 full planes (float4); H0 x-slice scattered
    // into transposed tile (4 b32 writes, stride 25 words -> conflict-free).
    for (int j = threadIdx.x; j < PP / 4; j += 192) {
        ((float4*)H1)[j] = ((const float4*)p1)[j];
        ((float4*)H2)[j] = ((const float4*)p2)[j];
    }
    for (int j = threadIdx.x; j < XS * NN / 4; j += 192) {
        const float4 v0 = ((const float4*)p0)[j];
        const int xl = (4 * j) / NN;
        const int k  = (4 * j) - xl * NN;   // multiple of 4, same row
        H0T[(k + 0) * XP + xl] = v0.x;
        H0T[(k + 1) * XP + xl] = v0.y;
        H0T[(k + 2) * XP + xl] = v0.z;
        H0T[(k + 3) * XP + xl] = v0.w;
    }
    __syncthreads();

    const int tx = threadIdx.x & 7;    // 8 x-tiles (3 wide)
    const int ty = threadIdx.x >> 3;   // 24 y-tiles (2 wide)
    const int x0 = tx * 3;
    const int y0 = ty * 2;

    // ---- product 1: S1 = H0 (x) H1 ----
    float acc[3][2];
    #pragma unroll
    for (int jx = 0; jx < 3; ++jx) {
        acc[jx][0] = -INFINITY; acc[jx][1] = -INFINITY;
    }

    #pragma unroll 4
    for (int kp = 0; kp < NN / 2; ++kp) {
        const int k = kp * 2;
        float a0[3], a1[3];
        #pragma unroll
        for (int jx = 0; jx < 3; ++jx) {
            a0[jx] = H0T[k * XP + x0 + jx];
            a1[jx] = H0T[(k + 1) * XP + x0 + jx];
        }
        const float2 bv0 = *(const float2*)&H1[k * NN + y0];
        const float2 bv1 = *(const float2*)&H1[(k + 1) * NN + y0];
        #pragma unroll
        for (int jx = 0; jx < 3; ++jx) {
            acc[jx][0] = fmaxf(acc[jx][0], fmaxf(a0[jx] + bv0.x, a1[jx] + bv1.x));
            acc[jx][1] = fmaxf(acc[jx][1], fmaxf(a0[jx] + bv0.y, a1[jx] + bv1.y));
        }
    }

    // S1T[y][x_local]: lanes step tx -> addr stride 3 words -> <=2-way aliasing
    #pragma unroll
    for (int jx = 0; jx < 3; ++jx) {
        S1T[(y0 + 0) * XP + x0 + jx] = acc[jx][0];
        S1T[(y0 + 1) * XP + x0 + jx] = acc[jx][1];
    }
    __syncthreads();

    // ---- product 2: S = S1 (x) H2, fused exp*weight epilogue ----
    float acc2[3][2];
    #pragma unroll
    for (int jx = 0; jx < 3; ++jx) {
        acc2[jx][0] = -INFINITY; acc2[jx][1] = -INFINITY;
    }

    #pragma unroll 4
    for (int kp = 0; kp < NN / 2; ++kp) {
        const int k = kp * 2;
        float a0[3], a1[3];
        #pragma unroll
        for (int jx = 0; jx < 3; ++jx) {
            a0[jx] = S1T[k * XP + x0 + jx];
            a1[jx] = S1T[(k + 1) * XP + x0 + jx];
        }
        const float2 bv0 = *(const float2*)&H2[k * NN + y0];
        const float2 bv1 = *(const float2*)&H2[(k + 1) * NN + y0];
        #pragma unroll
        for (int jx = 0; jx < 3; ++jx) {
            acc2[jx][0] = fmaxf(acc2[jx][0], fmaxf(a0[jx] + bv0.x, a1[jx] + bv1.x));
            acc2[jx][1] = fmaxf(acc2[jx][1], fmaxf(a0[jx] + bv0.y, a1[jx] + bv1.y));
        }
    }

    const float wgt = weights[c];
    float* outp = sw + (size_t)bc * PP;
    #pragma unroll
    for (int jx = 0; jx < 3; ++jx) {
        float2 o;
        o.x = __expf(acc2[jx][0]) * wgt;
        o.y = __expf(acc2[jx][1]) * wgt;
        *(float2*)&outp[(xbase + x0 + jx) * NN + y0] = o;
    }
}

// ---------------------------------------------------------------------------
// Kernel 2: combine. 4 threads per (b,x,y) — each handles one quad of 4
// triples.  lane = p (64-wide coalesced sw reads), quad = tid>>6.
// ---------------------------------------------------------------------------
__global__ __launch_bounds__(256) void combine_kernel(
    const float* __restrict__ sw,      // [B,Nc,N,N]
    const int*   __restrict__ mask,    // [B,N,N,R]
    const float* __restrict__ biases,  // [R]
    float*       __restrict__ out)     // [B,N,N,R]
{
    const int quad = threadIdx.x >> 6;                    // 0..3 (t-quad)
    const int pl   = blockIdx.x * 64 + (threadIdx.x & 63);// (b,p) linear
    const int b = pl / PP;
    const int p = pl - b * PP;

    const float* base = sw + (size_t)b * NC * PP + p;

    float acc[4];
    #pragma unroll
    for (int tt = 0; tt < 4; ++tt) {
        const int t = quad * 4 + tt;
        float s = biases[t];
        #pragma unroll
        for (int i = 0; i < NI; ++i)
            s += base[(size_t)(t * NI + i) * PP];
        acc[tt] = s;
    }

    const int4 m = *(const int4*)(mask + (size_t)pl * RR + quad * 4);
    float4 o;
    o.x = (m.x == 0) ? acc[0] : NEG;
    o.y = (m.y == 0) ? acc[1] : NEG;
    o.z = (m.z == 0) ? acc[2] : NEG;
    o.w = (m.w == 0) ? acc[3] : NEG;
    *(float4*)(out + (size_t)pl * RR + quad * 4) = o;
}

extern "C" void kernel_launch(void* const* d_in, const int* in_sizes, int n_in,
                              void* d_out, int out_size, void* d_ws, size_t ws_size,
                              hipStream_t stream)
{
    const float* trans   = (const float*)d_in[0];  // [B,N,N,T] f32
    const int*   mask    = (const int*)  d_in[1];  // [B,N,N,R] i32
    const int*   rules   = (const int*)  d_in[2];  // [Nc,3]    i32
    const float* weights = (const float*)d_in[3];  // [Nt,Ni]   f32
    const float* biases  = (const float*)d_in[4];  // [Nt]      f32
    float* out = (float*)d_out;

    float* tpose = (float*)d_ws;                   // [B,33,2304] = 1.22 MB
    float* sw    = tpose + (size_t)BB * TT * PP;   // [B,Nc,48,48] = 2.95 MB

    transpose_kernel<<<BB * 36, 256, 0, stream>>>(trans, tpose);

    chain_dp_kernel<<<BB * NC * 2, 192, 0, stream>>>(tpose, rules, weights, sw);

    combine_kernel<<<BB * PP / 64, 256, 0, stream>>>(sw, mask, biases, out);
}